// Round 12
// baseline (343.967 us; speedup 1.0000x reference)
//
#include <hip/hip_runtime.h>
#include <hip/hip_bf16.h>
#include <math.h>

typedef __attribute__((ext_vector_type(8))) short short8;
typedef __attribute__((ext_vector_type(4))) float f32x4;

#define DIM 256
#define NROWS 32768      // T*B*Ltot rows
#define PERT 2097152     // B*Ltot*D elements per timestep
#define SAMP_TOK 4096    // tokens per (t,b) sample

__device__ __forceinline__ float b2f(__hip_bfloat16 h){ return __bfloat162float(h); }
__device__ __forceinline__ __hip_bfloat16 f2b(float f){ return __float2bfloat16(f); }
__device__ __forceinline__ unsigned short f2bu(float f){
  __hip_bfloat16 h = __float2bfloat16(f);
  unsigned short u; __builtin_memcpy(&u, &h, 2); return u;
}

// async global -> LDS, 16B per lane (wave-uniform base + lane*16 on LDS side)
#define GLD_LDS16(gp, lp) __builtin_amdgcn_global_load_lds( \
    (const __attribute__((address_space(1))) unsigned int*)(gp), \
    (__attribute__((address_space(3))) unsigned int*)(lp), 16, 0, 0)

// branchless erf-based exact gelu (A&S 7.1.26, |err| <= ~3e-7: below bf16 ulp)
__device__ __forceinline__ float gelu_fast(float v){
  float z  = v * 0.70710678118654752f;
  float az = fabsf(z);
  float t  = __builtin_amdgcn_rcpf(fmaf(0.3275911f, az, 1.0f));
  float p  = fmaf(fmaf(fmaf(fmaf(1.061405429f, t, -1.453152027f), t,
                            1.421413741f), t, -0.284496736f), t, 0.254829592f);
  p *= t;
  float e  = __expf(-z * z);
  float y  = fmaf(-p, e, 1.0f);                 // erf(|z|)
  return fmaf(0.5f * fabsf(v), y, 0.5f * v);    // 0.5*v*(1+sign(v)*erf(|z|))
}

// ---------------- fp32 -> bf16 weight conversion (all 4 weights, one launch) ---
__global__ void f2ball_k(const float* __restrict__ w_qkv, const float* __restrict__ w_proj,
                         const float* __restrict__ w_f1, const float* __restrict__ w_f2,
                         __hip_bfloat16* __restrict__ o_qkv, __hip_bfloat16* __restrict__ o_proj,
                         __hip_bfloat16* __restrict__ o_f1, __hip_bfloat16* __restrict__ o_f2){
  int i = blockIdx.x * 256 + threadIdx.x;        // 0 .. 786431
  if (i < 196608)          o_qkv[i]           = f2b(w_qkv[i]);
  else if (i < 262144)     o_proj[i - 196608] = f2b(w_proj[i - 196608]);
  else if (i < 524288)     o_f1[i - 262144]   = f2b(w_f1[i - 262144]);
  else                     o_f2[i - 524288]   = f2b(w_f2[i - 524288]);
}

// ---------------- BN stats (branch 1): per-channel sum / sumsq -----------------
__global__ void bn_stats_k(const float* __restrict__ x, float* __restrict__ sum, float* __restrict__ sumsq){
  __shared__ __align__(16) float rs[4][256];
  __shared__ __align__(16) float rq[4][256];
  int t = threadIdx.x;
  int g = t & 63, r = t >> 6;
  size_t base = ((size_t)blockIdx.x * 128 + r) * DIM + g * 4;   // 128 rows per block
  float4 s = {0.f,0.f,0.f,0.f}, q = {0.f,0.f,0.f,0.f};
  for (int i = 0; i < 32; ++i){
    float4 v = *reinterpret_cast<const float4*>(x + base + (size_t)i * 4 * DIM);
    s.x += v.x; s.y += v.y; s.z += v.z; s.w += v.w;
    q.x += v.x*v.x; q.y += v.y*v.y; q.z += v.z*v.z; q.w += v.w*v.w;
  }
  *reinterpret_cast<float4*>(&rs[r][g*4]) = s;
  *reinterpret_cast<float4*>(&rq[r][g*4]) = q;
  __syncthreads();
  int c = t;   // one channel per thread
  atomicAdd(&sum[c],   rs[0][c] + rs[1][c] + rs[2][c] + rs[3][c]);
  atomicAdd(&sumsq[c], rq[0][c] + rq[1][c] + rq[2][c] + rq[3][c]);
}

__global__ void bn_fin_k(const float* __restrict__ sum, const float* __restrict__ sumsq,
                         const float* __restrict__ g, const float* __restrict__ b,
                         float* __restrict__ a_out, float* __restrict__ b_out){
  int c = threadIdx.x;
  float mean = sum[c] * (1.f/32768.f);
  float var  = sumsq[c] * (1.f/32768.f) - mean*mean;
  float a = g[c] / sqrtf(var + 1e-5f);
  a_out[c] = a;
  b_out[c] = b[c] - mean * a;
}

// ---------------- BN2 reduce: column-sum the 512x256 partial grids -------------
__global__ void bn_red_k(const float* __restrict__ pps, const float* __restrict__ ppq,
                         const float* __restrict__ g, const float* __restrict__ b,
                         float* __restrict__ a_out, float* __restrict__ b_out){
  int c = threadIdx.x;
  float s = 0.f, q = 0.f;
  for (int r = 0; r < 512; ++r){
    s += pps[r * 256 + c];
    q += ppq[r * 256 + c];
  }
  float mean = s * (1.f/32768.f);
  float var  = q * (1.f/32768.f) - mean*mean;
  float a = g[c] / sqrtf(var + 1e-5f);
  a_out[c] = a;
  b_out[c] = b[c] - mean * a;
}

// ---------------- LIF over T=4 (binary spike out, bf16 exact) ------------------
__global__ void lif_k(const float* __restrict__ x, const float* __restrict__ av,
                      const float* __restrict__ bv, __hip_bfloat16* __restrict__ s){
  int i = blockIdx.x * 256 + threadIdx.x;       // 0 .. PERT/4-1 (exact grid)
  int e4 = i * 4;
  int c4 = e4 & (DIM - 1);
  float4 a = *reinterpret_cast<const float4*>(av + c4);
  float4 b = *reinterpret_cast<const float4*>(bv + c4);
  float4 v = {0.f,0.f,0.f,0.f};
  #pragma unroll
  for (int t = 0; t < 4; ++t){
    float4 xn = *reinterpret_cast<const float4*>(x + (size_t)t * PERT + e4);
    xn.x = fmaf(xn.x, a.x, b.x); xn.y = fmaf(xn.y, a.y, b.y);
    xn.z = fmaf(xn.z, a.z, b.z); xn.w = fmaf(xn.w, a.w, b.w);
    v.x += (xn.x - v.x) * 0.5f; v.y += (xn.y - v.y) * 0.5f;
    v.z += (xn.z - v.z) * 0.5f; v.w += (xn.w - v.w) * 0.5f;
    ushort4 sp;
    sp.x = (v.x >= 1.0f) ? 0x3F80 : 0;  v.x = (v.x >= 1.0f) ? 0.f : v.x;
    sp.y = (v.y >= 1.0f) ? 0x3F80 : 0;  v.y = (v.y >= 1.0f) ? 0.f : v.y;
    sp.z = (v.z >= 1.0f) ? 0x3F80 : 0;  v.z = (v.z >= 1.0f) ? 0.f : v.z;
    sp.w = (v.w >= 1.0f) ? 0x3F80 : 0;  v.w = (v.w >= 1.0f) ? 0.f : v.w;
    *reinterpret_cast<ushort4*>(reinterpret_cast<unsigned short*>(s) + (size_t)t * PERT + e4) = sp;
  }
}

// ---------------- region means of binary s1 (exact fp32) -----------------------
__global__ void region_sum_k(const __hip_bfloat16* __restrict__ s, float* __restrict__ sm){
  __shared__ __align__(16) float red[4][256];
  int r = blockIdx.x, t = threadIdx.x;    // r = (sample*64 + region), 512 total
  int g = t & 63, sub = t >> 6;
  const unsigned short* sp = reinterpret_cast<const unsigned short*>(s);
  size_t base = ((size_t)r * 64 + sub * 16) * DIM + g * 4;
  float4 acc = {0.f,0.f,0.f,0.f};
  for (int i = 0; i < 16; ++i){
    ushort4 u = *reinterpret_cast<const ushort4*>(sp + base + (size_t)i * DIM);
    acc.x += (u.x != 0) ? 1.f : 0.f; acc.y += (u.y != 0) ? 1.f : 0.f;
    acc.z += (u.z != 0) ? 1.f : 0.f; acc.w += (u.w != 0) ? 1.f : 0.f;
  }
  *reinterpret_cast<float4*>(&red[sub][g*4]) = acc;
  __syncthreads();
  if (sub == 0){
    float4 o;
    o.x = (red[0][g*4+0] + red[1][g*4+0] + red[2][g*4+0] + red[3][g*4+0]) * 0.015625f;
    o.y = (red[0][g*4+1] + red[1][g*4+1] + red[2][g*4+1] + red[3][g*4+1]) * 0.015625f;
    o.z = (red[0][g*4+2] + red[1][g*4+2] + red[2][g*4+2] + red[3][g*4+2]) * 0.015625f;
    o.w = (red[0][g*4+3] + red[1][g*4+3] + red[2][g*4+3] + red[3][g*4+3]) * 0.015625f;
    *reinterpret_cast<float4*>(sm + (size_t)r * DIM + g * 4) = o;
  }
}

// ---------------- routing GEMM fp32: qkm[r][j] = smr[r]·qkv_w[j] + b[j], j<512 -
__global__ void rgemm_k(const float* __restrict__ smr, const float* __restrict__ w,
                        const float* __restrict__ bias, float* __restrict__ qkm){
  __shared__ float arow[256];
  int r = blockIdx.x, t = threadIdx.x;
  arow[t] = smr[(size_t)r * 256 + t];
  __syncthreads();
  for (int j = t; j < 512; j += 256){
    const float* wr = w + (size_t)j * 256;
    float acc = 0.f;
    for (int k = 0; k < 256; ++k) acc += arow[k] * wr[k];
    qkm[(size_t)r * 512 + j] = acc + bias[j];
  }
}

// ---------------- GEMM: C[M,N] = A[M,K] @ W[N,K]^T (+bias, epilogue) -----------
// (branch 1 only: EPI 0 = qkv bf16 out, EPI 1 = proj f32 + residual + bn2
//  partial stats, non-atomic)
template<int EPI>
__global__ __launch_bounds__(256) void gemm_bt(
    const __hip_bfloat16* __restrict__ A, const __hip_bfloat16* __restrict__ W,
    const float* __restrict__ bias, void* __restrict__ outp,
    const void* __restrict__ extra, const float* __restrict__ scaleptr,
    float* __restrict__ pps, float* __restrict__ ppq,
    int K, int N)
{
  __shared__ __align__(16) short As0[128 * 32];   // 8KB each, linear layout
  __shared__ __align__(16) short Ws0[128 * 32];
  __shared__ __align__(16) short As1[128 * 32];
  __shared__ __align__(16) short Ws1[128 * 32];
  int tid = threadIdx.x;
  int bm = blockIdx.x, bn = blockIdx.y;
  int lane = tid & 63;
  int l16 = lane & 15, quad = lane >> 4;
  int wv = tid >> 6;
  int wm = (wv >> 1) << 6, wn = (wv & 1) << 6;

  const int srow = tid >> 2;
  const int sq   = (tid & 3) ^ ((srow >> 1) & 3);
  const __hip_bfloat16* Ag = A + (size_t)(bm * 128 + srow) * K + (sq << 3);
  const __hip_bfloat16* Wg = W + (size_t)(bn * 128 + srow) * K + (sq << 3);
  const size_t rstep = (size_t)64 * K;

  int roA[4], roW[4];
  #pragma unroll
  for (int i = 0; i < 4; ++i){
    int Ra = wm + i * 16 + l16;
    roA[i] = Ra * 32 + ((quad ^ ((Ra >> 1) & 3)) << 3);
    int Rw = wn + i * 16 + l16;
    roW[i] = Rw * 32 + ((quad ^ ((Rw >> 1) & 3)) << 3);
  }

  f32x4 zero = {0.f, 0.f, 0.f, 0.f};
  f32x4 acc[4][4];
  #pragma unroll
  for (int i = 0; i < 4; ++i)
    #pragma unroll
    for (int j = 0; j < 4; ++j) acc[i][j] = zero;

  auto stage = [&](short* Ad, short* Wd, int k0){
    GLD_LDS16(Ag + k0,         Ad + tid * 8);
    GLD_LDS16(Ag + rstep + k0, Ad + tid * 8 + 2048);
    GLD_LDS16(Wg + k0,         Wd + tid * 8);
    GLD_LDS16(Wg + rstep + k0, Wd + tid * 8 + 2048);
  };
  auto compute = [&](const short* Asb, const short* Wsb){
    short8 af[4];
    #pragma unroll
    for (int mi = 0; mi < 4; ++mi)
      af[mi] = *reinterpret_cast<const short8*>(Asb + roA[mi]);
    #pragma unroll
    for (int ni = 0; ni < 4; ++ni){
      short8 wf = *reinterpret_cast<const short8*>(Wsb + roW[ni]);
      #pragma unroll
      for (int mi = 0; mi < 4; ++mi)
        acc[mi][ni] = __builtin_amdgcn_mfma_f32_16x16x32_bf16(wf, af[mi], acc[mi][ni], 0, 0, 0);
    }
  };

  stage(As0, Ws0, 0);
  __syncthreads();
  for (int k0 = 0; k0 < K; k0 += 64){
    if (k0 + 32 < K) stage(As1, Ws1, k0 + 32);
    compute(As0, Ws0);
    __syncthreads();
    if (k0 + 64 < K) stage(As0, Ws0, k0 + 64);
    if (k0 + 32 < K) compute(As1, Ws1);
    __syncthreads();
  }

  if (EPI == 0){
    // ---- coalesced bf16 epilogue: wave-private 64x64 C-tile via dead staging LDS
    short* Cw = (wv == 0) ? As0 : (wv == 1) ? Ws0 : (wv == 2) ? As1 : Ws1;
    #pragma unroll
    for (int ni = 0; ni < 4; ++ni){
      int col0 = (bn << 7) + wn + ni * 16 + (quad << 2);
      float4 bv = *reinterpret_cast<const float4*>(bias + col0);
      #pragma unroll
      for (int mi = 0; mi < 4; ++mi){
        float v0 = acc[mi][ni][0] + bv.x;
        float v1 = acc[mi][ni][1] + bv.y;
        float v2 = acc[mi][ni][2] + bv.z;
        float v3 = acc[mi][ni][3] + bv.w;
        unsigned lo = (unsigned)f2bu(v0) | ((unsigned)f2bu(v1) << 16);
        unsigned hi = (unsigned)f2bu(v2) | ((unsigned)f2bu(v3) << 16);
        int row = mi * 16 + l16;
        int cb  = (ni * 32 + (quad << 3)) ^ ((row & 7) << 4);
        *reinterpret_cast<uint2*>(reinterpret_cast<char*>(Cw) + row * 128 + cb) =
            make_uint2(lo, hi);
      }
    }
    asm volatile("s_waitcnt lgkmcnt(0)" ::: "memory");
    #pragma unroll
    for (int p = 0; p < 8; ++p){
      int row = p * 8 + (lane >> 3);
      int cb  = ((lane & 7) << 4) ^ ((row & 7) << 4);
      uint4 val = *reinterpret_cast<const uint4*>(
          reinterpret_cast<const char*>(Cw) + row * 128 + cb);
      int rowg = (bm << 7) + wm + row;
      int colg = (bn << 7) + wn + ((lane & 7) << 3);
      *reinterpret_cast<uint4*>((__hip_bfloat16*)outp + (size_t)rowg * N + colg) = val;
    }
  } else {
    // ---- f32 epilogue (proj): residual + fused bn2 partial stats (non-atomic)
    float sc = scaleptr[0];
    float4 ts[4], tq[4];
    #pragma unroll
    for (int ni = 0; ni < 4; ++ni){ ts[ni] = {0.f,0.f,0.f,0.f}; tq[ni] = {0.f,0.f,0.f,0.f}; }
    #pragma unroll
    for (int ni = 0; ni < 4; ++ni){
      int col0 = (bn << 7) + wn + ni * 16 + (quad << 2);
      float4 bv = *reinterpret_cast<const float4*>(bias + col0);
      #pragma unroll
      for (int mi = 0; mi < 4; ++mi){
        int rowg = (bm << 7) + wm + mi * 16 + l16;
        size_t off = (size_t)rowg * N + col0;
        float v0 = acc[mi][ni][0] + bv.x;
        float v1 = acc[mi][ni][1] + bv.y;
        float v2 = acc[mi][ni][2] + bv.z;
        float v3 = acc[mi][ni][3] + bv.w;
        float4 xr = *reinterpret_cast<const float4*>((const float*)extra + off);
        float4 ov;
        ov.x = xr.x + v0 * sc; ov.y = xr.y + v1 * sc;
        ov.z = xr.z + v2 * sc; ov.w = xr.w + v3 * sc;
        *reinterpret_cast<float4*>((float*)outp + off) = ov;
        ts[ni].x += ov.x; ts[ni].y += ov.y; ts[ni].z += ov.z; ts[ni].w += ov.w;
        tq[ni].x += ov.x*ov.x; tq[ni].y += ov.y*ov.y;
        tq[ni].z += ov.z*ov.z; tq[ni].w += ov.w*ov.w;
      }
    }
    int prow = (bm << 1) + (wm >> 6);
    #pragma unroll
    for (int ni = 0; ni < 4; ++ni){
      float4 S = ts[ni], Q = tq[ni];
      #pragma unroll
      for (int m = 1; m < 16; m <<= 1){
        S.x += __shfl_xor(S.x, m); S.y += __shfl_xor(S.y, m);
        S.z += __shfl_xor(S.z, m); S.w += __shfl_xor(S.w, m);
        Q.x += __shfl_xor(Q.x, m); Q.y += __shfl_xor(Q.y, m);
        Q.z += __shfl_xor(Q.z, m); Q.w += __shfl_xor(Q.w, m);
      }
      if (l16 == 0){
        int col0 = (bn << 7) + wn + ni * 16 + (quad << 2);
        *reinterpret_cast<float4*>(pps + prow * 256 + col0) = S;
        *reinterpret_cast<float4*>(ppq + prow * 256 + col0) = Q;
      }
    }
  }
}

// ---------------- FUSED FFN: out = x2 + (gelu(s2@W1^T+b1)@W2^T+b2)*scale -------
// 512 threads / 8 waves per 64-row block, 2 blocks/CU (80KB LDS each).
// R12 vs R11: A-res and h use FRAGMENT-MAJOR layouts [k-granule][row] with 16B
// row stride -- every MFMA fragment read is 16 consecutive 16B slots, h writes
// hit 8 distinct mod-128 slots x 2 lanes: conflict-free BY CONSTRUCTION, no XOR.
// (R11's multi-level XOR on the A-res read measured 4-way conflicted: +4.2M
// SQ_LDS_BANK_CONFLICT. Block-private arrays don't need swizzles at all if the
// layout is chosen fragment-major.)  W1/W2 slab paths + schedule unchanged.
// LDS (shorts): A-res [0,16384) = [G 0..31][row 0..63][8]  |  S0 [16384,24576)
// | S1 [24576,32768) | h [32768,40960) = [Gc 0..15][row 0..63][8]. 80KB total.
__global__ __launch_bounds__(512, 4) void ffn_fused_k(
    const __hip_bfloat16* __restrict__ A,   // s2 [32768,256]
    const __hip_bfloat16* __restrict__ W1,  // [1024,256] bf16
    const float* __restrict__ b1,
    const __hip_bfloat16* __restrict__ W2,  // [256,1024] bf16
    const float* __restrict__ b2,
    float* __restrict__ x2,                 // in/out [32768,256] f32
    const float* __restrict__ scaleptr)
{
  __shared__ __align__(16) short lds[40960];   // 80KB exactly
  const int tid = threadIdx.x;                 // 0..511
  const int bm = blockIdx.x;                   // 512 blocks x 64 rows
  const int lane = tid & 63;
  const int l16 = lane & 15, quad = lane >> 4;
  const int wv = tid >> 6;                     // wave 0..7

  const int S0 = 16384, S1 = 24576, H = 32768; // short offsets

  // ---- staging source addressing (W slabs keep R10's proven swizzles) ----
  const int w1r = tid >> 3, w1s = tid & 7;                  // W1 granule: row, slot
  const int w1q = (w1s ^ (w1r & 7)) << 3;
  const int w2r = tid >> 2, w2s = tid & 3;                  // W2 granule: row, slot
  const int w2q = (w2s ^ ((w2r >> 1) & 3)) << 3;            // involution over (row>>1)&3

  // ---- read offsets (shorts) ----
  // A-res fragment-major: granule G = k*8 + kh*4 + quad, offset G*512 + Ra*8.
  int roAb[4][2];                       // base w/o k-term: [mi][kh]; add k*4096
  #pragma unroll
  for (int mi = 0; mi < 4; ++mi){
    int Ra = mi * 16 + l16;
    #pragma unroll
    for (int kh = 0; kh < 2; ++kh)
      roAb[mi][kh] = ((kh << 2) | quad) * 512 + Ra * 8;
  }
  int roW1[2];
  {
    int Rw = wv * 16 + l16;
    #pragma unroll
    for (int kh = 0; kh < 2; ++kh)
      roW1[kh] = Rw * 64 + ((((kh << 5) | (quad << 3)) ^ ((Rw & 7) << 3)));
  }
  // h fragment-major: write Gc = wv*2+(quad>>1), sub-off (quad&1)*4 (8B);
  // read Gc = kk*4+quad -> base quad*512, add kk*2048.
  int hwr[4], hrb[4];
  #pragma unroll
  for (int mi = 0; mi < 4; ++mi){
    int row = mi * 16 + l16;
    hwr[mi] = H + (wv * 2 + (quad >> 1)) * 512 + row * 8 + (quad & 1) * 4;
    hrb[mi] = H + quad * 512 + row * 8;
  }
  int roW2[2];
  #pragma unroll
  for (int ni = 0; ni < 2; ++ni){
    int Rw = wv * 32 + ni * 16 + l16;
    roW2[ni] = Rw * 32 + (((quad ^ ((Rw >> 1) & 3))) << 3);
  }

  f32x4 zero = {0.f, 0.f, 0.f, 0.f};
  f32x4 acc2[4][2];
  #pragma unroll
  for (int i = 0; i < 4; ++i){ acc2[i][0] = zero; acc2[i][1] = zero; }

  float sc = scaleptr[0];

  // stage W1 K-step for chunk cc into slab S: W1[128 rows x 64 k] = 16KB
  auto stageW1 = [&](int S, int cc, int k0){
    const __hip_bfloat16* g = W1 + (size_t)(cc * 128 + w1r) * 256 + k0 + w1q;
    GLD_LDS16(g,            lds + S + tid * 8);
    GLD_LDS16(g + 64 * 256, lds + S + 4096 + tid * 8);
  };
  auto stageW2 = [&](int S, int cc, int kk){
    const __hip_bfloat16* p = W2 + (size_t)w2r * 1024 + cc * 128 + kk * 32 + w2q;
    GLD_LDS16(p,               lds + S + tid * 8);
    GLD_LDS16(p + 128 * 1024,  lds + S + 4096 + tid * 8);
  };

  // ---- A-resident staging, fragment-major: wave w stages granule-column
  //      G = p*8 + wv (64 rows x 16B = contiguous 1KB dest per wave).
  #pragma unroll
  for (int p = 0; p < 4; ++p){
    int G = p * 8 + wv;
    GLD_LDS16(A + (size_t)(bm * 64 + lane) * 256 + G * 8, lds + G * 512 + lane * 8);
  }
  stageW1(S0, 0, 0);
  __syncthreads();

  for (int c1 = 0; c1 < 8; ++c1){
    f32x4 acc1[4];
    #pragma unroll
    for (int i = 0; i < 4; ++i) acc1[i] = zero;

    // ---- GEMM1: 4 K-steps of 64, W1 double-buffered, A resident ----
    #pragma unroll
    for (int k = 0; k < 4; ++k){
      const int cur = (k & 1) ? S1 : S0;
      const int nxt = (k & 1) ? S0 : S1;
      if (k < 3) stageW1(nxt, c1, (k + 1) * 64);
      #pragma unroll
      for (int kh = 0; kh < 2; ++kh){
        short8 wf = *reinterpret_cast<const short8*>(lds + cur + roW1[kh]);
        #pragma unroll
        for (int mi = 0; mi < 4; ++mi){
          short8 af = *reinterpret_cast<const short8*>(lds + roAb[mi][kh] + k * 4096);
          acc1[mi] = __builtin_amdgcn_mfma_f32_16x16x32_bf16(wf, af, acc1[mi], 0, 0, 0);
        }
      }
      __syncthreads();
    }

    // ---- W2 slice 0 prefetch (lands under gelu VALU work) ----
    stageW2(S0, c1, 0);

    // ---- bias + gelu + pack h (fragment-major) ----
    {
      int colg = c1 * 128 + wv * 16 + quad * 4;
      float4 bv = *reinterpret_cast<const float4*>(b1 + colg);
      #pragma unroll
      for (int mi = 0; mi < 4; ++mi){
        float g0 = gelu_fast(acc1[mi][0] + bv.x);
        float g1 = gelu_fast(acc1[mi][1] + bv.y);
        float g2 = gelu_fast(acc1[mi][2] + bv.z);
        float g3 = gelu_fast(acc1[mi][3] + bv.w);
        unsigned lo = (unsigned)f2bu(g0) | ((unsigned)f2bu(g1) << 16);
        unsigned hi = (unsigned)f2bu(g2) | ((unsigned)f2bu(g3) << 16);
        *reinterpret_cast<uint2*>(lds + hwr[mi]) = make_uint2(lo, hi);
      }
    }
    __syncthreads();   // h visible + W2_0 landed

    // ---- GEMM2 partial: acc2 += h[64x128] @ W2[:, c1]^T, 4 k-steps dbuf.
    //      At kk==3 stage next c1's W1 step-0 into S0 (S0 last W2-read kk=2).
    #pragma unroll
    for (int kk = 0; kk < 4; ++kk){
      const int cur = (kk & 1) ? S1 : S0;
      const int nxt = (kk & 1) ? S0 : S1;
      if (kk < 3)            stageW2(nxt, c1, kk + 1);
      else if (c1 < 7)       stageW1(S0, c1 + 1, 0);
      short8 af[4];
      #pragma unroll
      for (int mi = 0; mi < 4; ++mi)
        af[mi] = *reinterpret_cast<const short8*>(lds + hrb[mi] + kk * 2048);
      #pragma unroll
      for (int ni = 0; ni < 2; ++ni){
        short8 wf = *reinterpret_cast<const short8*>(lds + cur + roW2[ni]);
        #pragma unroll
        for (int mi = 0; mi < 4; ++mi)
          acc2[mi][ni] = __builtin_amdgcn_mfma_f32_16x16x32_bf16(wf, af[mi], acc2[mi][ni], 0, 0, 0);
      }
      __syncthreads();
    }
  }

  // ---- epilogue: out = x2 + (acc2 + b2)*scale, float4 (full-sector stores)
  #pragma unroll
  for (int ni = 0; ni < 2; ++ni){
    int col0 = wv * 32 + ni * 16 + (quad << 2);
    float4 bv = *reinterpret_cast<const float4*>(b2 + col0);
    #pragma unroll
    for (int mi = 0; mi < 4; ++mi){
      int rowg = bm * 64 + mi * 16 + l16;
      size_t off = (size_t)rowg * 256 + col0;
      float4 xr = *reinterpret_cast<const float4*>(x2 + off);
      float4 ov;
      ov.x = xr.x + (acc2[mi][ni][0] + bv.x) * sc;
      ov.y = xr.y + (acc2[mi][ni][1] + bv.y) * sc;
      ov.z = xr.z + (acc2[mi][ni][2] + bv.z) * sc;
      ov.w = xr.w + (acc2[mi][ni][3] + bv.w) * sc;
      *reinterpret_cast<float4*>(x2 + off) = ov;
    }
  }
}

// ---------------- top-k routing: aff = qm @ km^T per sample, pick top-4 --------
__global__ void topk_k(const float* __restrict__ qkm, int* __restrict__ idx){
  __shared__ float aff[64];
  int r = blockIdx.x;           // sample*64 + query region
  int m = threadIdx.x;          // candidate region 0..63
  int b = r >> 6;
  const float4* qrow = reinterpret_cast<const float4*>(qkm + (size_t)r * 512);
  const float4* krow = reinterpret_cast<const float4*>(qkm + (size_t)(b * 64 + m) * 512 + 256);
  float dot = 0.f;
  for (int d = 0; d < 64; ++d){
    float4 qv = qrow[d], kv = krow[d];
    dot += qv.x * kv.x + qv.y * kv.y + qv.z * kv.z + qv.w * kv.w;
  }
  aff[m] = dot;
  __syncthreads();
  if (m == 0){
    #pragma unroll
    for (int t = 0; t < 4; ++t){
      float best = -INFINITY; int bi = 0;
      for (int i = 0; i < 64; ++i){
        if (aff[i] > best){ best = aff[i]; bi = i; }   // strict >: lowest index on ties (jax top_k)
      }
      aff[bi] = -INFINITY;
      idx[r * 4 + t] = bi;
    }
  }
}

// ---------------- MFMA routed attention: block per (region, head) --------------
// P region at short-offset 8448 (Vt needs only [0,8448); Ks tail dead after the
// post-S barrier). LDS 50688 B => 3 blocks/CU (12 waves/CU).
__global__ __launch_bounds__(256) void attn_mfma_k(
    const __hip_bfloat16* __restrict__ qkv, const int* __restrict__ idx,
    __hip_bfloat16* __restrict__ o_out, int rbase)
{
  __shared__ __align__(16) short lds[25344];   // 50688 B
  const int rl = blockIdx.x;       // local region in this chunk
  const int h  = blockIdx.y;       // head
  const int rg = rbase + rl;       // global region (for idx)
  const int bl = rl >> 6;          // local sample
  const int tid = threadIdx.x;
  const int w = tid >> 6, lane = tid & 63;
  const int l16 = lane & 15, quad = lane >> 4;
  short* Pw = lds + 8448 + w * 4224;

  const int reg = idx[rg * 4 + (tid >> 6)] & 63;       // clamp: never OOB
  const size_t srow = (size_t)bl * SAMP_TOK + (size_t)reg * 64 + (tid & 63);
  const __hip_bfloat16* kvsrc = qkv + srow * 768 + 256 + (size_t)h * 32;

  const size_t qrow = (size_t)rl * 64 + w * 16 + l16;
  short8 qf = *reinterpret_cast<const short8*>(qkv + qrow * 768 + (size_t)h * 32 + quad * 8);

  uint4 vreg[4];
  #pragma unroll
  for (int c = 0; c < 4; ++c)
    vreg[c] = *reinterpret_cast<const uint4*>(kvsrc + 256 + c * 8);

  // K -> Ks[token][40] occupies [0,10240); its tail overlaps the P region,
  // which is only written after the post-S barrier (Ks dead by then).
  #pragma unroll
  for (int c = 0; c < 4; ++c)
    *reinterpret_cast<uint4*>(&lds[tid * 40 + c * 8]) =
      *reinterpret_cast<const uint4*>(kvsrc + c * 8);
  __syncthreads();

  f32x4 s[16];
  #pragma unroll
  for (int nt = 0; nt < 16; ++nt){
    short8 kf = *reinterpret_cast<const short8*>(&lds[(nt * 16 + l16) * 40 + quad * 8]);
    f32x4 z = {0.f, 0.f, 0.f, 0.f};
    s[nt] = __builtin_amdgcn_mfma_f32_16x16x32_bf16(kf, qf, z, 0, 0, 0);
  }
  __syncthreads();   // all waves done reading Ks -> whole Ks region reusable

  #pragma unroll
  for (int c = 0; c < 4; ++c){
    short8 vv = *reinterpret_cast<short8*>(&vreg[c]);
    #pragma unroll
    for (int e = 0; e < 8; ++e)
      lds[(c * 8 + e) * 264 + tid] = vv[e];
  }

  float mx = -1e30f;
  #pragma unroll
  for (int nt = 0; nt < 16; ++nt)
    #pragma unroll
    for (int r = 0; r < 4; ++r) mx = fmaxf(mx, s[nt][r]);
  mx = fmaxf(mx, __shfl_xor(mx, 16));
  mx = fmaxf(mx, __shfl_xor(mx, 32));
  float den = 0.f;
  #pragma unroll
  for (int nt = 0; nt < 16; ++nt)
    #pragma unroll
    for (int r = 0; r < 4; ++r){
      float e = __expf((s[nt][r] - mx) * 0.17677669529663687f);  // scale folded in
      s[nt][r] = e; den += e;
    }
  den += __shfl_xor(den, 16);
  den += __shfl_xor(den, 32);

  #pragma unroll
  for (int nt = 0; nt < 16; ++nt){
    unsigned lo = (unsigned)f2bu(s[nt][0]) | ((unsigned)f2bu(s[nt][1]) << 16);
    unsigned hi = (unsigned)f2bu(s[nt][2]) | ((unsigned)f2bu(s[nt][3]) << 16);
    *reinterpret_cast<uint2*>(&Pw[l16 * 264 + nt * 16 + quad * 4]) = make_uint2(lo, hi);
  }
  __syncthreads();

  f32x4 o0 = {0.f, 0.f, 0.f, 0.f}, o1 = o0;
  #pragma unroll
  for (int kk = 0; kk < 8; ++kk){
    short8 pb = *reinterpret_cast<const short8*>(&Pw[l16 * 264 + kk * 32 + quad * 8]);
    short8 a0 = *reinterpret_cast<const short8*>(&lds[l16 * 264 + kk * 32 + quad * 8]);
    short8 a1 = *reinterpret_cast<const short8*>(&lds[(16 + l16) * 264 + kk * 32 + quad * 8]);
    o0 = __builtin_amdgcn_mfma_f32_16x16x32_bf16(a0, pb, o0, 0, 0, 0);
    o1 = __builtin_amdgcn_mfma_f32_16x16x32_bf16(a1, pb, o1, 0, 0, 0);
  }
  float inv = 1.f / den;
  size_t obase = ((size_t)rl * 64 + w * 16 + l16) * 256 + (size_t)h * 32;
  unsigned pk0 = (unsigned)f2bu(o0[0] * inv) | ((unsigned)f2bu(o0[1] * inv) << 16);
  unsigned pk1 = (unsigned)f2bu(o0[2] * inv) | ((unsigned)f2bu(o0[3] * inv) << 16);
  unsigned pk2 = (unsigned)f2bu(o1[0] * inv) | ((unsigned)f2bu(o1[1] * inv) << 16);
  unsigned pk3 = (unsigned)f2bu(o1[2] * inv) | ((unsigned)f2bu(o1[3] * inv) << 16);
  *reinterpret_cast<uint2*>(o_out + obase + quad * 4)      = make_uint2(pk0, pk1);
  *reinterpret_cast<uint2*>(o_out + obase + 16 + quad * 4) = make_uint2(pk2, pk3);
}

// -------------------------------------------------------------------------------
// STRICT ws budget (never write beyond ws_size):
//   [0,4MB)   misc: BN sums/coeffs, idxb, smr, qkm, bf16 weights, bn2 partials
//   [4,20MB)  s1 (branch1) then s2 (branch2), bf16 16MB
//   [20MB,..) chunk buffers (branch1 only now), adaptively sized from ws_size.
// x2 (fp32 [32768,256], 32MB) lives in d_out; fused FFN updates d_out in place.
// Minimum ws_size supported: 28MB.
extern "C" void kernel_launch(void* const* d_in, const int* in_sizes, int n_in,
                              void* d_out, int out_size, void* d_ws, size_t ws_size,
                              hipStream_t stream)
{
  const float* x      = (const float*)d_in[0];
  const float* bn1_g  = (const float*)d_in[1];
  const float* bn1_b  = (const float*)d_in[2];
  const float* bn2_g  = (const float*)d_in[3];
  const float* bn2_b  = (const float*)d_in[4];
  const float* qkv_w  = (const float*)d_in[5];
  const float* qkv_b  = (const float*)d_in[6];
  const float* proj_w = (const float*)d_in[7];
  const float* proj_b = (const float*)d_in[8];
  const float* ffn_w1 = (const float*)d_in[9];
  const float* ffn_b1 = (const float*)d_in[10];
  const float* ffn_w2 = (const float*)d_in[11];
  const float* ffn_b2 = (const float*)d_in[12];
  const float* scale  = (const float*)d_in[13];
  float* x2 = (float*)d_out;       // residual lives in d_out

  char* ws = (char*)d_ws;
  const size_t MB = 1024 * 1024;
  float* sum1 = (float*)(ws + 0);
  float* sq1  = (float*)(ws + 1024);
  float* a1   = (float*)(ws + 4096);
  float* b1   = (float*)(ws + 5120);
  float* a2   = (float*)(ws + 6144);
  float* b2   = (float*)(ws + 7168);
  int*   idxb = (int*)(ws + 8192);                              // 8KB
  float* smr  = (float*)(ws + 16384);                           // 512KB
  float* qkm  = (float*)(ws + 540672);                          // 1MB
  __hip_bfloat16* qkv_wb  = (__hip_bfloat16*)(ws + 1589248);    // 384KB
  __hip_bfloat16* proj_wb = (__hip_bfloat16*)(ws + 1982464);    // 128KB
  __hip_bfloat16* ffn_w1b = (__hip_bfloat16*)(ws + 2113536);    // 512KB
  __hip_bfloat16* ffn_w2b = (__hip_bfloat16*)(ws + 2637824);    // 512KB, ends 3162112
  float* ppsum = (float*)(ws + 3162112);                        // 512KB (512x256 f32)
  float* ppsq  = (float*)(ws + 3686400);                        // 512KB, ends 4MB exactly
  __hip_bfloat16* s1 = (__hip_bfloat16*)(ws + 4 * MB);          // 16MB (s2 reuses)
  __hip_bfloat16* s2 = s1;
  char* chunkbuf = ws + 20 * MB;

  // adaptive chunk sizes from ws_size (constant across calls -> graph-safe)
  size_t avail = (ws_size > 20 * MB) ? (ws_size - 20 * MB) : (8 * MB);
  int nc = (avail >= 64 * MB) ? 8 : (avail >= 32 * MB) ? 4 : (avail >= 16 * MB) ? 2 : 1;   // samples/chunk (8MB each)

  __hip_bfloat16* qkvc = (__hip_bfloat16*)chunkbuf;                        // nc*6MB
  __hip_bfloat16* oc   = (__hip_bfloat16*)(chunkbuf + (size_t)nc * 6 * MB); // nc*2MB

  hipMemsetAsync(d_ws, 0, 4096, stream);   // zero BN1 accumulators

  // one-time weight conversions fp32 -> bf16 (single launch)
  f2ball_k<<<3072, 256, 0, stream>>>(qkv_w, proj_w, ffn_w1, ffn_w2,
                                     qkv_wb, proj_wb, ffn_w1b, ffn_w2b);

  // branch 1: BN -> LIF -> routing, then per-chunk qkv -> attn -> proj+residual
  bn_stats_k<<<256, 256, 0, stream>>>(x, sum1, sq1);
  bn_fin_k<<<1, 256, 0, stream>>>(sum1, sq1, bn1_g, bn1_b, a1, b1);
  lif_k<<<PERT / 1024, 256, 0, stream>>>(x, a1, b1, s1);
  region_sum_k<<<512, 256, 0, stream>>>(s1, smr);
  rgemm_k<<<512, 256, 0, stream>>>(smr, qkv_w, qkv_b, qkm);   // fp32 routing (flip-proof)
  topk_k<<<512, 64, 0, stream>>>(qkm, idxb);

  const int nchunkA = 8 / nc;
  for (int c = 0; c < nchunkA; ++c){
    const size_t ro = (size_t)c * nc * SAMP_TOK;            // row offset (tokens)
    gemm_bt<0><<<dim3(nc * SAMP_TOK / 128, 6), 256, 0, stream>>>(
        s1 + ro * 256, qkv_wb, qkv_b, qkvc, nullptr, nullptr, nullptr, nullptr, 256, 768);
    attn_mfma_k<<<dim3(nc * 64, 8), 256, 0, stream>>>(qkvc, idxb, oc, c * nc * 64);
    gemm_bt<1><<<dim3(nc * SAMP_TOK / 128, 2), 256, 0, stream>>>(
        oc, proj_wb, proj_b, x2 + ro * 256, x + ro * 256, scale,
        ppsum + (ro >> 6) * 256, ppsq + (ro >> 6) * 256, 256, 256);
  }

  // branch 2: bn2 partial-reduce (atomic-free) -> LIF -> fused FFN (in-place)
  bn_red_k<<<1, 256, 0, stream>>>(ppsum, ppsq, bn2_g, bn2_b, a2, b2);
  lif_k<<<PERT / 1024, 256, 0, stream>>>(x2, a2, b2, s2);
  ffn_fused_k<<<512, 512, 0, stream>>>(s2, ffn_w1b, ffn_b1, ffn_w2b, ffn_b2, x2, scale);
}

// Round 13
// 338.577 us; speedup vs baseline: 1.0159x; 1.0159x over previous
//
#include <hip/hip_runtime.h>
#include <hip/hip_bf16.h>
#include <math.h>

typedef __attribute__((ext_vector_type(8))) short short8;
typedef __attribute__((ext_vector_type(4))) float f32x4;

#define DIM 256
#define NROWS 32768      // T*B*Ltot rows
#define PERT 2097152     // B*Ltot*D elements per timestep
#define SAMP_TOK 4096    // tokens per (t,b) sample

__device__ __forceinline__ float b2f(__hip_bfloat16 h){ return __bfloat162float(h); }
__device__ __forceinline__ __hip_bfloat16 f2b(float f){ return __float2bfloat16(f); }
__device__ __forceinline__ unsigned short f2bu(float f){
  __hip_bfloat16 h = __float2bfloat16(f);
  unsigned short u; __builtin_memcpy(&u, &h, 2); return u;
}

// async global -> LDS, 16B per lane (wave-uniform base + lane*16 on LDS side)
#define GLD_LDS16(gp, lp) __builtin_amdgcn_global_load_lds( \
    (const __attribute__((address_space(1))) unsigned int*)(gp), \
    (__attribute__((address_space(3))) unsigned int*)(lp), 16, 0, 0)

// branchless erf-based exact gelu (A&S 7.1.26, |err| <= ~3e-7: below bf16 ulp)
__device__ __forceinline__ float gelu_fast(float v){
  float z  = v * 0.70710678118654752f;
  float az = fabsf(z);
  float t  = __builtin_amdgcn_rcpf(fmaf(0.3275911f, az, 1.0f));
  float p  = fmaf(fmaf(fmaf(fmaf(1.061405429f, t, -1.453152027f), t,
                            1.421413741f), t, -0.284496736f), t, 0.254829592f);
  p *= t;
  float e  = __expf(-z * z);
  float y  = fmaf(-p, e, 1.0f);                 // erf(|z|)
  return fmaf(0.5f * fabsf(v), y, 0.5f * v);    // 0.5*v*(1+sign(v)*erf(|z|))
}

// ---------------- fp32 -> bf16 weight conversion (all 4 weights, one launch) ---
__global__ void f2ball_k(const float* __restrict__ w_qkv, const float* __restrict__ w_proj,
                         const float* __restrict__ w_f1, const float* __restrict__ w_f2,
                         __hip_bfloat16* __restrict__ o_qkv, __hip_bfloat16* __restrict__ o_proj,
                         __hip_bfloat16* __restrict__ o_f1, __hip_bfloat16* __restrict__ o_f2){
  int i = blockIdx.x * 256 + threadIdx.x;        // 0 .. 786431
  if (i < 196608)          o_qkv[i]           = f2b(w_qkv[i]);
  else if (i < 262144)     o_proj[i - 196608] = f2b(w_proj[i - 196608]);
  else if (i < 524288)     o_f1[i - 262144]   = f2b(w_f1[i - 262144]);
  else                     o_f2[i - 524288]   = f2b(w_f2[i - 524288]);
}

// ---------------- BN stats (branch 1): per-channel sum / sumsq -----------------
__global__ void bn_stats_k(const float* __restrict__ x, float* __restrict__ sum, float* __restrict__ sumsq){
  __shared__ __align__(16) float rs[4][256];
  __shared__ __align__(16) float rq[4][256];
  int t = threadIdx.x;
  int g = t & 63, r = t >> 6;
  size_t base = ((size_t)blockIdx.x * 128 + r) * DIM + g * 4;   // 128 rows per block
  float4 s = {0.f,0.f,0.f,0.f}, q = {0.f,0.f,0.f,0.f};
  for (int i = 0; i < 32; ++i){
    float4 v = *reinterpret_cast<const float4*>(x + base + (size_t)i * 4 * DIM);
    s.x += v.x; s.y += v.y; s.z += v.z; s.w += v.w;
    q.x += v.x*v.x; q.y += v.y*v.y; q.z += v.z*v.z; q.w += v.w*v.w;
  }
  *reinterpret_cast<float4*>(&rs[r][g*4]) = s;
  *reinterpret_cast<float4*>(&rq[r][g*4]) = q;
  __syncthreads();
  int c = t;   // one channel per thread
  atomicAdd(&sum[c],   rs[0][c] + rs[1][c] + rs[2][c] + rs[3][c]);
  atomicAdd(&sumsq[c], rq[0][c] + rq[1][c] + rq[2][c] + rq[3][c]);
}

__global__ void bn_fin_k(const float* __restrict__ sum, const float* __restrict__ sumsq,
                         const float* __restrict__ g, const float* __restrict__ b,
                         float* __restrict__ a_out, float* __restrict__ b_out){
  int c = threadIdx.x;
  float mean = sum[c] * (1.f/32768.f);
  float var  = sumsq[c] * (1.f/32768.f) - mean*mean;
  float a = g[c] / sqrtf(var + 1e-5f);
  a_out[c] = a;
  b_out[c] = b[c] - mean * a;
}

// ---------------- BN2 reduce: column-sum the 512x256 partial grids -------------
__global__ void bn_red_k(const float* __restrict__ pps, const float* __restrict__ ppq,
                         const float* __restrict__ g, const float* __restrict__ b,
                         float* __restrict__ a_out, float* __restrict__ b_out){
  int c = threadIdx.x;
  float s = 0.f, q = 0.f;
  for (int r = 0; r < 512; ++r){
    s += pps[r * 256 + c];
    q += ppq[r * 256 + c];
  }
  float mean = s * (1.f/32768.f);
  float var  = q * (1.f/32768.f) - mean*mean;
  float a = g[c] / sqrtf(var + 1e-5f);
  a_out[c] = a;
  b_out[c] = b[c] - mean * a;
}

// ---------------- LIF over T=4 (binary spike out, bf16 exact) ------------------
__global__ void lif_k(const float* __restrict__ x, const float* __restrict__ av,
                      const float* __restrict__ bv, __hip_bfloat16* __restrict__ s){
  int i = blockIdx.x * 256 + threadIdx.x;       // 0 .. PERT/4-1 (exact grid)
  int e4 = i * 4;
  int c4 = e4 & (DIM - 1);
  float4 a = *reinterpret_cast<const float4*>(av + c4);
  float4 b = *reinterpret_cast<const float4*>(bv + c4);
  float4 v = {0.f,0.f,0.f,0.f};
  #pragma unroll
  for (int t = 0; t < 4; ++t){
    float4 xn = *reinterpret_cast<const float4*>(x + (size_t)t * PERT + e4);
    xn.x = fmaf(xn.x, a.x, b.x); xn.y = fmaf(xn.y, a.y, b.y);
    xn.z = fmaf(xn.z, a.z, b.z); xn.w = fmaf(xn.w, a.w, b.w);
    v.x += (xn.x - v.x) * 0.5f; v.y += (xn.y - v.y) * 0.5f;
    v.z += (xn.z - v.z) * 0.5f; v.w += (xn.w - v.w) * 0.5f;
    ushort4 sp;
    sp.x = (v.x >= 1.0f) ? 0x3F80 : 0;  v.x = (v.x >= 1.0f) ? 0.f : v.x;
    sp.y = (v.y >= 1.0f) ? 0x3F80 : 0;  v.y = (v.y >= 1.0f) ? 0.f : v.y;
    sp.z = (v.z >= 1.0f) ? 0x3F80 : 0;  v.z = (v.z >= 1.0f) ? 0.f : v.z;
    sp.w = (v.w >= 1.0f) ? 0x3F80 : 0;  v.w = (v.w >= 1.0f) ? 0.f : v.w;
    *reinterpret_cast<ushort4*>(reinterpret_cast<unsigned short*>(s) + (size_t)t * PERT + e4) = sp;
  }
}

// ---------------- region means of binary s1 (exact fp32) -----------------------
__global__ void region_sum_k(const __hip_bfloat16* __restrict__ s, float* __restrict__ sm){
  __shared__ __align__(16) float red[4][256];
  int r = blockIdx.x, t = threadIdx.x;    // r = (sample*64 + region), 512 total
  int g = t & 63, sub = t >> 6;
  const unsigned short* sp = reinterpret_cast<const unsigned short*>(s);
  size_t base = ((size_t)r * 64 + sub * 16) * DIM + g * 4;
  float4 acc = {0.f,0.f,0.f,0.f};
  for (int i = 0; i < 16; ++i){
    ushort4 u = *reinterpret_cast<const ushort4*>(sp + base + (size_t)i * DIM);
    acc.x += (u.x != 0) ? 1.f : 0.f; acc.y += (u.y != 0) ? 1.f : 0.f;
    acc.z += (u.z != 0) ? 1.f : 0.f; acc.w += (u.w != 0) ? 1.f : 0.f;
  }
  *reinterpret_cast<float4*>(&red[sub][g*4]) = acc;
  __syncthreads();
  if (sub == 0){
    float4 o;
    o.x = (red[0][g*4+0] + red[1][g*4+0] + red[2][g*4+0] + red[3][g*4+0]) * 0.015625f;
    o.y = (red[0][g*4+1] + red[1][g*4+1] + red[2][g*4+1] + red[3][g*4+1]) * 0.015625f;
    o.z = (red[0][g*4+2] + red[1][g*4+2] + red[2][g*4+2] + red[3][g*4+2]) * 0.015625f;
    o.w = (red[0][g*4+3] + red[1][g*4+3] + red[2][g*4+3] + red[3][g*4+3]) * 0.015625f;
    *reinterpret_cast<float4*>(sm + (size_t)r * DIM + g * 4) = o;
  }
}

// ---------------- routing GEMM fp32: qkm[r][j] = smr[r]·qkv_w[j] + b[j], j<512 -
__global__ void rgemm_k(const float* __restrict__ smr, const float* __restrict__ w,
                        const float* __restrict__ bias, float* __restrict__ qkm){
  __shared__ float arow[256];
  int r = blockIdx.x, t = threadIdx.x;
  arow[t] = smr[(size_t)r * 256 + t];
  __syncthreads();
  for (int j = t; j < 512; j += 256){
    const float* wr = w + (size_t)j * 256;
    float acc = 0.f;
    for (int k = 0; k < 256; ++k) acc += arow[k] * wr[k];
    qkm[(size_t)r * 512 + j] = acc + bias[j];
  }
}

// ---------------- qkv GEMM: C[M,768] = A[M,256] @ W[768,256]^T + bias (bf16) ---
// (former gemm_bt EPI0 path; 128x128 tile, 2-phase dbuf, coalesced epilogue)
__global__ __launch_bounds__(256) void gemm_qkv_k(
    const __hip_bfloat16* __restrict__ A, const __hip_bfloat16* __restrict__ W,
    const float* __restrict__ bias, __hip_bfloat16* __restrict__ outp,
    int K, int N)
{
  __shared__ __align__(16) short As0[128 * 32];   // 8KB each, linear layout
  __shared__ __align__(16) short Ws0[128 * 32];
  __shared__ __align__(16) short As1[128 * 32];
  __shared__ __align__(16) short Ws1[128 * 32];
  int tid = threadIdx.x;
  int bm = blockIdx.x, bn = blockIdx.y;
  int lane = tid & 63;
  int l16 = lane & 15, quad = lane >> 4;
  int wv = tid >> 6;
  int wm = (wv >> 1) << 6, wn = (wv & 1) << 6;

  const int srow = tid >> 2;
  const int sq   = (tid & 3) ^ ((srow >> 1) & 3);
  const __hip_bfloat16* Ag = A + (size_t)(bm * 128 + srow) * K + (sq << 3);
  const __hip_bfloat16* Wg = W + (size_t)(bn * 128 + srow) * K + (sq << 3);
  const size_t rstep = (size_t)64 * K;

  int roA[4], roW[4];
  #pragma unroll
  for (int i = 0; i < 4; ++i){
    int Ra = wm + i * 16 + l16;
    roA[i] = Ra * 32 + ((quad ^ ((Ra >> 1) & 3)) << 3);
    int Rw = wn + i * 16 + l16;
    roW[i] = Rw * 32 + ((quad ^ ((Rw >> 1) & 3)) << 3);
  }

  f32x4 zero = {0.f, 0.f, 0.f, 0.f};
  f32x4 acc[4][4];
  #pragma unroll
  for (int i = 0; i < 4; ++i)
    #pragma unroll
    for (int j = 0; j < 4; ++j) acc[i][j] = zero;

  auto stage = [&](short* Ad, short* Wd, int k0){
    GLD_LDS16(Ag + k0,         Ad + tid * 8);
    GLD_LDS16(Ag + rstep + k0, Ad + tid * 8 + 2048);
    GLD_LDS16(Wg + k0,         Wd + tid * 8);
    GLD_LDS16(Wg + rstep + k0, Wd + tid * 8 + 2048);
  };
  auto compute = [&](const short* Asb, const short* Wsb){
    short8 af[4];
    #pragma unroll
    for (int mi = 0; mi < 4; ++mi)
      af[mi] = *reinterpret_cast<const short8*>(Asb + roA[mi]);
    #pragma unroll
    for (int ni = 0; ni < 4; ++ni){
      short8 wf = *reinterpret_cast<const short8*>(Wsb + roW[ni]);
      #pragma unroll
      for (int mi = 0; mi < 4; ++mi)
        acc[mi][ni] = __builtin_amdgcn_mfma_f32_16x16x32_bf16(wf, af[mi], acc[mi][ni], 0, 0, 0);
    }
  };

  stage(As0, Ws0, 0);
  __syncthreads();
  for (int k0 = 0; k0 < K; k0 += 64){
    if (k0 + 32 < K) stage(As1, Ws1, k0 + 32);
    compute(As0, Ws0);
    __syncthreads();
    if (k0 + 64 < K) stage(As0, Ws0, k0 + 64);
    if (k0 + 32 < K) compute(As1, Ws1);
    __syncthreads();
  }

  // coalesced bf16 epilogue: wave-private 64x64 C-tile via dead staging LDS
  short* Cw = (wv == 0) ? As0 : (wv == 1) ? Ws0 : (wv == 2) ? As1 : Ws1;
  #pragma unroll
  for (int ni = 0; ni < 4; ++ni){
    int col0 = (bn << 7) + wn + ni * 16 + (quad << 2);
    float4 bv = *reinterpret_cast<const float4*>(bias + col0);
    #pragma unroll
    for (int mi = 0; mi < 4; ++mi){
      float v0 = acc[mi][ni][0] + bv.x;
      float v1 = acc[mi][ni][1] + bv.y;
      float v2 = acc[mi][ni][2] + bv.z;
      float v3 = acc[mi][ni][3] + bv.w;
      unsigned lo = (unsigned)f2bu(v0) | ((unsigned)f2bu(v1) << 16);
      unsigned hi = (unsigned)f2bu(v2) | ((unsigned)f2bu(v3) << 16);
      int row = mi * 16 + l16;
      int cb  = (ni * 32 + (quad << 3)) ^ ((row & 7) << 4);
      *reinterpret_cast<uint2*>(reinterpret_cast<char*>(Cw) + row * 128 + cb) =
          make_uint2(lo, hi);
    }
  }
  asm volatile("s_waitcnt lgkmcnt(0)" ::: "memory");
  #pragma unroll
  for (int p = 0; p < 8; ++p){
    int row = p * 8 + (lane >> 3);
    int cb  = ((lane & 7) << 4) ^ ((row & 7) << 4);
    uint4 val = *reinterpret_cast<const uint4*>(
        reinterpret_cast<const char*>(Cw) + row * 128 + cb);
    int rowg = (bm << 7) + wm + row;
    int colg = (bn << 7) + wn + ((lane & 7) << 3);
    *reinterpret_cast<uint4*>(outp + (size_t)rowg * N + colg) = val;
  }
}

// ---------------- proj GEMM (64-row blocks, 1Mx4N waves): x2 = x + (oc@Wp^T+b)*s
// R13: proj was the last 2-blocks/CU latency-bound kernel (grid (256,2), 8
// waves/CU -- the exact R8-ffn starvation signature). BM=64 with all 4 waves
// split in N doubles resident blocks to 4/CU (16 waves/CU, R9's proven fix).
// 1Mx4N layout keeps exactly ONE writer per bn2-partial cell (prow = bm).
// LDS 24KB; same staging/read swizzle pair as gemm_qkv_k; fused bn2 partials.
__global__ __launch_bounds__(256) void gemm_proj_k(
    const __hip_bfloat16* __restrict__ A,   // oc [32768,256] bf16
    const __hip_bfloat16* __restrict__ W,   // proj_wb [256,256] bf16
    const float* __restrict__ bias, float* __restrict__ outp,
    const float* __restrict__ extra, const float* __restrict__ scaleptr,
    float* __restrict__ pps, float* __restrict__ ppq)
{
  const int K = 256, N = 256;
  __shared__ __align__(16) short As0[64 * 32];    // 4KB
  __shared__ __align__(16) short Ws0[128 * 32];   // 8KB
  __shared__ __align__(16) short As1[64 * 32];
  __shared__ __align__(16) short Ws1[128 * 32];
  int tid = threadIdx.x;
  int bm = blockIdx.x, bn = blockIdx.y;           // bm: 64-row group, bn: 128-col
  int lane = tid & 63;
  int l16 = lane & 15, quad = lane >> 4;
  int wv = tid >> 6;                              // wave 0..3, N-split only

  const int sr = tid >> 2;                        // 0..63
  const int sq = (tid & 3) ^ ((sr >> 1) & 3);
  const __hip_bfloat16* Ag = A + (size_t)(bm * 64  + sr) * K + (sq << 3);
  const __hip_bfloat16* Wg = W + (size_t)(bn * 128 + sr) * K + (sq << 3);

  int roA[4], roW[2];
  #pragma unroll
  for (int mi = 0; mi < 4; ++mi){
    int Ra = mi * 16 + l16;
    roA[mi] = Ra * 32 + ((quad ^ ((Ra >> 1) & 3)) << 3);
  }
  #pragma unroll
  for (int ni = 0; ni < 2; ++ni){
    int Rw = wv * 32 + ni * 16 + l16;
    roW[ni] = Rw * 32 + ((quad ^ ((Rw >> 1) & 3)) << 3);
  }

  f32x4 zero = {0.f, 0.f, 0.f, 0.f};
  f32x4 acc[4][2];
  #pragma unroll
  for (int i = 0; i < 4; ++i){ acc[i][0] = zero; acc[i][1] = zero; }

  auto stage = [&](short* Ad, short* Wd, int k0){
    GLD_LDS16(Ag + k0,                  Ad + tid * 8);
    GLD_LDS16(Wg + k0,                  Wd + tid * 8);
    GLD_LDS16(Wg + (size_t)64 * K + k0, Wd + tid * 8 + 2048);
  };
  auto compute = [&](const short* Asb, const short* Wsb){
    short8 af[4];
    #pragma unroll
    for (int mi = 0; mi < 4; ++mi)
      af[mi] = *reinterpret_cast<const short8*>(Asb + roA[mi]);
    #pragma unroll
    for (int ni = 0; ni < 2; ++ni){
      short8 wf = *reinterpret_cast<const short8*>(Wsb + roW[ni]);
      #pragma unroll
      for (int mi = 0; mi < 4; ++mi)
        acc[mi][ni] = __builtin_amdgcn_mfma_f32_16x16x32_bf16(wf, af[mi], acc[mi][ni], 0, 0, 0);
    }
  };

  stage(As0, Ws0, 0);
  __syncthreads();
  for (int k0 = 0; k0 < K; k0 += 64){
    if (k0 + 32 < K) stage(As1, Ws1, k0 + 32);
    compute(As0, Ws0);
    __syncthreads();
    if (k0 + 64 < K) stage(As0, Ws0, k0 + 64);
    if (k0 + 32 < K) compute(As1, Ws1);
    __syncthreads();
  }

  // epilogue: residual + fused bn2 partial stats (non-atomic, one writer/cell)
  float sc = scaleptr[0];
  float4 ts[2], tq[2];
  #pragma unroll
  for (int ni = 0; ni < 2; ++ni){ ts[ni] = {0.f,0.f,0.f,0.f}; tq[ni] = {0.f,0.f,0.f,0.f}; }
  #pragma unroll
  for (int ni = 0; ni < 2; ++ni){
    int col0 = (bn << 7) + wv * 32 + ni * 16 + (quad << 2);
    float4 bv = *reinterpret_cast<const float4*>(bias + col0);
    #pragma unroll
    for (int mi = 0; mi < 4; ++mi){
      int rowg = bm * 64 + mi * 16 + l16;
      size_t off = (size_t)rowg * N + col0;
      float v0 = acc[mi][ni][0] + bv.x;
      float v1 = acc[mi][ni][1] + bv.y;
      float v2 = acc[mi][ni][2] + bv.z;
      float v3 = acc[mi][ni][3] + bv.w;
      float4 xr = *reinterpret_cast<const float4*>(extra + off);
      float4 ov;
      ov.x = xr.x + v0 * sc; ov.y = xr.y + v1 * sc;
      ov.z = xr.z + v2 * sc; ov.w = xr.w + v3 * sc;
      *reinterpret_cast<float4*>(outp + off) = ov;
      ts[ni].x += ov.x; ts[ni].y += ov.y; ts[ni].z += ov.z; ts[ni].w += ov.w;
      tq[ni].x += ov.x*ov.x; tq[ni].y += ov.y*ov.y;
      tq[ni].z += ov.z*ov.z; tq[ni].w += ov.w*ov.w;
    }
  }
  #pragma unroll
  for (int ni = 0; ni < 2; ++ni){
    float4 S = ts[ni], Q = tq[ni];
    #pragma unroll
    for (int m = 1; m < 16; m <<= 1){
      S.x += __shfl_xor(S.x, m); S.y += __shfl_xor(S.y, m);
      S.z += __shfl_xor(S.z, m); S.w += __shfl_xor(S.w, m);
      Q.x += __shfl_xor(Q.x, m); Q.y += __shfl_xor(Q.y, m);
      Q.z += __shfl_xor(Q.z, m); Q.w += __shfl_xor(Q.w, m);
    }
    if (l16 == 0){
      int col0 = (bn << 7) + wv * 32 + ni * 16 + (quad << 2);
      *reinterpret_cast<float4*>(pps + bm * 256 + col0) = S;
      *reinterpret_cast<float4*>(ppq + bm * 256 + col0) = Q;
    }
  }
}

// ---------------- FUSED FFN: out = x2 + (gelu(s2@W1^T+b1)@W2^T+b2)*scale -------
// (R12 frozen: fragment-major A-res/h, conflict-free by construction; 80KB LDS,
// 8 waves x 64-row blocks, 2 blocks/CU. At its drain-structure floor.)
__global__ __launch_bounds__(512, 4) void ffn_fused_k(
    const __hip_bfloat16* __restrict__ A,   // s2 [32768,256]
    const __hip_bfloat16* __restrict__ W1,  // [1024,256] bf16
    const float* __restrict__ b1,
    const __hip_bfloat16* __restrict__ W2,  // [256,1024] bf16
    const float* __restrict__ b2,
    float* __restrict__ x2,                 // in/out [32768,256] f32
    const float* __restrict__ scaleptr)
{
  __shared__ __align__(16) short lds[40960];   // 80KB exactly
  const int tid = threadIdx.x;                 // 0..511
  const int bm = blockIdx.x;                   // 512 blocks x 64 rows
  const int lane = tid & 63;
  const int l16 = lane & 15, quad = lane >> 4;
  const int wv = tid >> 6;                     // wave 0..7

  const int S0 = 16384, S1 = 24576, H = 32768; // short offsets

  const int w1r = tid >> 3, w1s = tid & 7;                  // W1 granule: row, slot
  const int w1q = (w1s ^ (w1r & 7)) << 3;
  const int w2r = tid >> 2, w2s = tid & 3;                  // W2 granule: row, slot
  const int w2q = (w2s ^ ((w2r >> 1) & 3)) << 3;            // involution over (row>>1)&3

  int roAb[4][2];                       // A-res fragment-major base: [mi][kh]
  #pragma unroll
  for (int mi = 0; mi < 4; ++mi){
    int Ra = mi * 16 + l16;
    #pragma unroll
    for (int kh = 0; kh < 2; ++kh)
      roAb[mi][kh] = ((kh << 2) | quad) * 512 + Ra * 8;
  }
  int roW1[2];
  {
    int Rw = wv * 16 + l16;
    #pragma unroll
    for (int kh = 0; kh < 2; ++kh)
      roW1[kh] = Rw * 64 + ((((kh << 5) | (quad << 3)) ^ ((Rw & 7) << 3)));
  }
  int hwr[4], hrb[4];
  #pragma unroll
  for (int mi = 0; mi < 4; ++mi){
    int row = mi * 16 + l16;
    hwr[mi] = H + (wv * 2 + (quad >> 1)) * 512 + row * 8 + (quad & 1) * 4;
    hrb[mi] = H + quad * 512 + row * 8;
  }
  int roW2[2];
  #pragma unroll
  for (int ni = 0; ni < 2; ++ni){
    int Rw = wv * 32 + ni * 16 + l16;
    roW2[ni] = Rw * 32 + (((quad ^ ((Rw >> 1) & 3))) << 3);
  }

  f32x4 zero = {0.f, 0.f, 0.f, 0.f};
  f32x4 acc2[4][2];
  #pragma unroll
  for (int i = 0; i < 4; ++i){ acc2[i][0] = zero; acc2[i][1] = zero; }

  float sc = scaleptr[0];

  auto stageW1 = [&](int S, int cc, int k0){
    const __hip_bfloat16* g = W1 + (size_t)(cc * 128 + w1r) * 256 + k0 + w1q;
    GLD_LDS16(g,            lds + S + tid * 8);
    GLD_LDS16(g + 64 * 256, lds + S + 4096 + tid * 8);
  };
  auto stageW2 = [&](int S, int cc, int kk){
    const __hip_bfloat16* p = W2 + (size_t)w2r * 1024 + cc * 128 + kk * 32 + w2q;
    GLD_LDS16(p,               lds + S + tid * 8);
    GLD_LDS16(p + 128 * 1024,  lds + S + 4096 + tid * 8);
  };

  #pragma unroll
  for (int p = 0; p < 4; ++p){
    int G = p * 8 + wv;
    GLD_LDS16(A + (size_t)(bm * 64 + lane) * 256 + G * 8, lds + G * 512 + lane * 8);
  }
  stageW1(S0, 0, 0);
  __syncthreads();

  for (int c1 = 0; c1 < 8; ++c1){
    f32x4 acc1[4];
    #pragma unroll
    for (int i = 0; i < 4; ++i) acc1[i] = zero;

    #pragma unroll
    for (int k = 0; k < 4; ++k){
      const int cur = (k & 1) ? S1 : S0;
      const int nxt = (k & 1) ? S0 : S1;
      if (k < 3) stageW1(nxt, c1, (k + 1) * 64);
      #pragma unroll
      for (int kh = 0; kh < 2; ++kh){
        short8 wf = *reinterpret_cast<const short8*>(lds + cur + roW1[kh]);
        #pragma unroll
        for (int mi = 0; mi < 4; ++mi){
          short8 af = *reinterpret_cast<const short8*>(lds + roAb[mi][kh] + k * 4096);
          acc1[mi] = __builtin_amdgcn_mfma_f32_16x16x32_bf16(wf, af, acc1[mi], 0, 0, 0);
        }
      }
      __syncthreads();
    }

    stageW2(S0, c1, 0);

    {
      int colg = c1 * 128 + wv * 16 + quad * 4;
      float4 bv = *reinterpret_cast<const float4*>(b1 + colg);
      #pragma unroll
      for (int mi = 0; mi < 4; ++mi){
        float g0 = gelu_fast(acc1[mi][0] + bv.x);
        float g1 = gelu_fast(acc1[mi][1] + bv.y);
        float g2 = gelu_fast(acc1[mi][2] + bv.z);
        float g3 = gelu_fast(acc1[mi][3] + bv.w);
        unsigned lo = (unsigned)f2bu(g0) | ((unsigned)f2bu(g1) << 16);
        unsigned hi = (unsigned)f2bu(g2) | ((unsigned)f2bu(g3) << 16);
        *reinterpret_cast<uint2*>(lds + hwr[mi]) = make_uint2(lo, hi);
      }
    }
    __syncthreads();   // h visible + W2_0 landed

    #pragma unroll
    for (int kk = 0; kk < 4; ++kk){
      const int cur = (kk & 1) ? S1 : S0;
      const int nxt = (kk & 1) ? S0 : S1;
      if (kk < 3)            stageW2(nxt, c1, kk + 1);
      else if (c1 < 7)       stageW1(S0, c1 + 1, 0);
      short8 af[4];
      #pragma unroll
      for (int mi = 0; mi < 4; ++mi)
        af[mi] = *reinterpret_cast<const short8*>(lds + hrb[mi] + kk * 2048);
      #pragma unroll
      for (int ni = 0; ni < 2; ++ni){
        short8 wf = *reinterpret_cast<const short8*>(lds + cur + roW2[ni]);
        #pragma unroll
        for (int mi = 0; mi < 4; ++mi)
          acc2[mi][ni] = __builtin_amdgcn_mfma_f32_16x16x32_bf16(wf, af[mi], acc2[mi][ni], 0, 0, 0);
      }
      __syncthreads();
    }
  }

  #pragma unroll
  for (int ni = 0; ni < 2; ++ni){
    int col0 = wv * 32 + ni * 16 + (quad << 2);
    float4 bv = *reinterpret_cast<const float4*>(b2 + col0);
    #pragma unroll
    for (int mi = 0; mi < 4; ++mi){
      int rowg = bm * 64 + mi * 16 + l16;
      size_t off = (size_t)rowg * 256 + col0;
      float4 xr = *reinterpret_cast<const float4*>(x2 + off);
      float4 ov;
      ov.x = xr.x + (acc2[mi][ni][0] + bv.x) * sc;
      ov.y = xr.y + (acc2[mi][ni][1] + bv.y) * sc;
      ov.z = xr.z + (acc2[mi][ni][2] + bv.z) * sc;
      ov.w = xr.w + (acc2[mi][ni][3] + bv.w) * sc;
      *reinterpret_cast<float4*>(x2 + off) = ov;
    }
  }
}

// ---------------- top-k routing: aff = qm @ km^T per sample, pick top-4 --------
__global__ void topk_k(const float* __restrict__ qkm, int* __restrict__ idx){
  __shared__ float aff[64];
  int r = blockIdx.x;           // sample*64 + query region
  int m = threadIdx.x;          // candidate region 0..63
  int b = r >> 6;
  const float4* qrow = reinterpret_cast<const float4*>(qkm + (size_t)r * 512);
  const float4* krow = reinterpret_cast<const float4*>(qkm + (size_t)(b * 64 + m) * 512 + 256);
  float dot = 0.f;
  for (int d = 0; d < 64; ++d){
    float4 qv = qrow[d], kv = krow[d];
    dot += qv.x * kv.x + qv.y * kv.y + qv.z * kv.z + qv.w * kv.w;
  }
  aff[m] = dot;
  __syncthreads();
  if (m == 0){
    #pragma unroll
    for (int t = 0; t < 4; ++t){
      float best = -INFINITY; int bi = 0;
      for (int i = 0; i < 64; ++i){
        if (aff[i] > best){ best = aff[i]; bi = i; }   // strict >: lowest index on ties (jax top_k)
      }
      aff[bi] = -INFINITY;
      idx[r * 4 + t] = bi;
    }
  }
}

// ---------------- MFMA routed attention: block per (region, head) --------------
// P region at short-offset 8448 (Vt needs only [0,8448); Ks tail dead after the
// post-S barrier). LDS 50688 B => 3 blocks/CU (12 waves/CU).
__global__ __launch_bounds__(256) void attn_mfma_k(
    const __hip_bfloat16* __restrict__ qkv, const int* __restrict__ idx,
    __hip_bfloat16* __restrict__ o_out, int rbase)
{
  __shared__ __align__(16) short lds[25344];   // 50688 B
  const int rl = blockIdx.x;       // local region in this chunk
  const int h  = blockIdx.y;       // head
  const int rg = rbase + rl;       // global region (for idx)
  const int bl = rl >> 6;          // local sample
  const int tid = threadIdx.x;
  const int w = tid >> 6, lane = tid & 63;
  const int l16 = lane & 15, quad = lane >> 4;
  short* Pw = lds + 8448 + w * 4224;

  const int reg = idx[rg * 4 + (tid >> 6)] & 63;       // clamp: never OOB
  const size_t srow = (size_t)bl * SAMP_TOK + (size_t)reg * 64 + (tid & 63);
  const __hip_bfloat16* kvsrc = qkv + srow * 768 + 256 + (size_t)h * 32;

  const size_t qrow = (size_t)rl * 64 + w * 16 + l16;
  short8 qf = *reinterpret_cast<const short8*>(qkv + qrow * 768 + (size_t)h * 32 + quad * 8);

  uint4 vreg[4];
  #pragma unroll
  for (int c = 0; c < 4; ++c)
    vreg[c] = *reinterpret_cast<const uint4*>(kvsrc + 256 + c * 8);

  // K -> Ks[token][40] occupies [0,10240); its tail overlaps the P region,
  // which is only written after the post-S barrier (Ks dead by then).
  #pragma unroll
  for (int c = 0; c < 4; ++c)
    *reinterpret_cast<uint4*>(&lds[tid * 40 + c * 8]) =
      *reinterpret_cast<const uint4*>(kvsrc + c * 8);
  __syncthreads();

  f32x4 s[16];
  #pragma unroll
  for (int nt = 0; nt < 16; ++nt){
    short8 kf = *reinterpret_cast<const short8*>(&lds[(nt * 16 + l16) * 40 + quad * 8]);
    f32x4 z = {0.f, 0.f, 0.f, 0.f};
    s[nt] = __builtin_amdgcn_mfma_f32_16x16x32_bf16(kf, qf, z, 0, 0, 0);
  }
  __syncthreads();   // all waves done reading Ks -> whole Ks region reusable

  #pragma unroll
  for (int c = 0; c < 4; ++c){
    short8 vv = *reinterpret_cast<short8*>(&vreg[c]);
    #pragma unroll
    for (int e = 0; e < 8; ++e)
      lds[(c * 8 + e) * 264 + tid] = vv[e];
  }

  float mx = -1e30f;
  #pragma unroll
  for (int nt = 0; nt < 16; ++nt)
    #pragma unroll
    for (int r = 0; r < 4; ++r) mx = fmaxf(mx, s[nt][r]);
  mx = fmaxf(mx, __shfl_xor(mx, 16));
  mx = fmaxf(mx, __shfl_xor(mx, 32));
  float den = 0.f;
  #pragma unroll
  for (int nt = 0; nt < 16; ++nt)
    #pragma unroll
    for (int r = 0; r < 4; ++r){
      float e = __expf((s[nt][r] - mx) * 0.17677669529663687f);  // scale folded in
      s[nt][r] = e; den += e;
    }
  den += __shfl_xor(den, 16);
  den += __shfl_xor(den, 32);

  #pragma unroll
  for (int nt = 0; nt < 16; ++nt){
    unsigned lo = (unsigned)f2bu(s[nt][0]) | ((unsigned)f2bu(s[nt][1]) << 16);
    unsigned hi = (unsigned)f2bu(s[nt][2]) | ((unsigned)f2bu(s[nt][3]) << 16);
    *reinterpret_cast<uint2*>(&Pw[l16 * 264 + nt * 16 + quad * 4]) = make_uint2(lo, hi);
  }
  __syncthreads();

  f32x4 o0 = {0.f, 0.f, 0.f, 0.f}, o1 = o0;
  #pragma unroll
  for (int kk = 0; kk < 8; ++kk){
    short8 pb = *reinterpret_cast<const short8*>(&Pw[l16 * 264 + kk * 32 + quad * 8]);
    short8 a0 = *reinterpret_cast<const short8*>(&lds[l16 * 264 + kk * 32 + quad * 8]);
    short8 a1 = *reinterpret_cast<const short8*>(&lds[(16 + l16) * 264 + kk * 32 + quad * 8]);
    o0 = __builtin_amdgcn_mfma_f32_16x16x32_bf16(a0, pb, o0, 0, 0, 0);
    o1 = __builtin_amdgcn_mfma_f32_16x16x32_bf16(a1, pb, o1, 0, 0, 0);
  }
  float inv = 1.f / den;
  size_t obase = ((size_t)rl * 64 + w * 16 + l16) * 256 + (size_t)h * 32;
  unsigned pk0 = (unsigned)f2bu(o0[0] * inv) | ((unsigned)f2bu(o0[1] * inv) << 16);
  unsigned pk1 = (unsigned)f2bu(o0[2] * inv) | ((unsigned)f2bu(o0[3] * inv) << 16);
  unsigned pk2 = (unsigned)f2bu(o1[0] * inv) | ((unsigned)f2bu(o1[1] * inv) << 16);
  unsigned pk3 = (unsigned)f2bu(o1[2] * inv) | ((unsigned)f2bu(o1[3] * inv) << 16);
  *reinterpret_cast<uint2*>(o_out + obase + quad * 4)      = make_uint2(pk0, pk1);
  *reinterpret_cast<uint2*>(o_out + obase + 16 + quad * 4) = make_uint2(pk2, pk3);
}

// -------------------------------------------------------------------------------
// STRICT ws budget (never write beyond ws_size):
//   [0,4MB)   misc: BN sums/coeffs, idxb, smr, qkm, bf16 weights, bn2 partials
//   [4,20MB)  s1 (branch1) then s2 (branch2), bf16 16MB
//   [20MB,..) chunk buffers (branch1 only now), adaptively sized from ws_size.
// x2 (fp32 [32768,256], 32MB) lives in d_out; fused FFN updates d_out in place.
// Minimum ws_size supported: 28MB.
extern "C" void kernel_launch(void* const* d_in, const int* in_sizes, int n_in,
                              void* d_out, int out_size, void* d_ws, size_t ws_size,
                              hipStream_t stream)
{
  const float* x      = (const float*)d_in[0];
  const float* bn1_g  = (const float*)d_in[1];
  const float* bn1_b  = (const float*)d_in[2];
  const float* bn2_g  = (const float*)d_in[3];
  const float* bn2_b  = (const float*)d_in[4];
  const float* qkv_w  = (const float*)d_in[5];
  const float* qkv_b  = (const float*)d_in[6];
  const float* proj_w = (const float*)d_in[7];
  const float* proj_b = (const float*)d_in[8];
  const float* ffn_w1 = (const float*)d_in[9];
  const float* ffn_b1 = (const float*)d_in[10];
  const float* ffn_w2 = (const float*)d_in[11];
  const float* ffn_b2 = (const float*)d_in[12];
  const float* scale  = (const float*)d_in[13];
  float* x2 = (float*)d_out;       // residual lives in d_out

  char* ws = (char*)d_ws;
  const size_t MB = 1024 * 1024;
  float* sum1 = (float*)(ws + 0);
  float* sq1  = (float*)(ws + 1024);
  float* a1   = (float*)(ws + 4096);
  float* b1   = (float*)(ws + 5120);
  float* a2   = (float*)(ws + 6144);
  float* b2   = (float*)(ws + 7168);
  int*   idxb = (int*)(ws + 8192);                              // 8KB
  float* smr  = (float*)(ws + 16384);                           // 512KB
  float* qkm  = (float*)(ws + 540672);                          // 1MB
  __hip_bfloat16* qkv_wb  = (__hip_bfloat16*)(ws + 1589248);    // 384KB
  __hip_bfloat16* proj_wb = (__hip_bfloat16*)(ws + 1982464);    // 128KB
  __hip_bfloat16* ffn_w1b = (__hip_bfloat16*)(ws + 2113536);    // 512KB
  __hip_bfloat16* ffn_w2b = (__hip_bfloat16*)(ws + 2637824);    // 512KB, ends 3162112
  float* ppsum = (float*)(ws + 3162112);                        // 512KB (512x256 f32)
  float* ppsq  = (float*)(ws + 3686400);                        // 512KB, ends 4MB exactly
  __hip_bfloat16* s1 = (__hip_bfloat16*)(ws + 4 * MB);          // 16MB (s2 reuses)
  __hip_bfloat16* s2 = s1;
  char* chunkbuf = ws + 20 * MB;

  // adaptive chunk sizes from ws_size (constant across calls -> graph-safe)
  size_t avail = (ws_size > 20 * MB) ? (ws_size - 20 * MB) : (8 * MB);
  int nc = (avail >= 64 * MB) ? 8 : (avail >= 32 * MB) ? 4 : (avail >= 16 * MB) ? 2 : 1;   // samples/chunk (8MB each)

  __hip_bfloat16* qkvc = (__hip_bfloat16*)chunkbuf;                        // nc*6MB
  __hip_bfloat16* oc   = (__hip_bfloat16*)(chunkbuf + (size_t)nc * 6 * MB); // nc*2MB

  hipMemsetAsync(d_ws, 0, 4096, stream);   // zero BN1 accumulators

  // one-time weight conversions fp32 -> bf16 (single launch)
  f2ball_k<<<3072, 256, 0, stream>>>(qkv_w, proj_w, ffn_w1, ffn_w2,
                                     qkv_wb, proj_wb, ffn_w1b, ffn_w2b);

  // branch 1: BN -> LIF -> routing, then per-chunk qkv -> attn -> proj+residual
  bn_stats_k<<<256, 256, 0, stream>>>(x, sum1, sq1);
  bn_fin_k<<<1, 256, 0, stream>>>(sum1, sq1, bn1_g, bn1_b, a1, b1);
  lif_k<<<PERT / 1024, 256, 0, stream>>>(x, a1, b1, s1);
  region_sum_k<<<512, 256, 0, stream>>>(s1, smr);
  rgemm_k<<<512, 256, 0, stream>>>(smr, qkv_w, qkv_b, qkm);   // fp32 routing (flip-proof)
  topk_k<<<512, 64, 0, stream>>>(qkm, idxb);

  const int nchunkA = 8 / nc;
  for (int c = 0; c < nchunkA; ++c){
    const size_t ro = (size_t)c * nc * SAMP_TOK;            // row offset (tokens)
    gemm_qkv_k<<<dim3(nc * SAMP_TOK / 128, 6), 256, 0, stream>>>(
        s1 + ro * 256, qkv_wb, qkv_b, qkvc, 256, 768);
    attn_mfma_k<<<dim3(nc * 64, 8), 256, 0, stream>>>(qkvc, idxb, oc, c * nc * 64);
    gemm_proj_k<<<dim3(nc * SAMP_TOK / 64, 2), 256, 0, stream>>>(
        oc, proj_wb, proj_b, x2 + ro * 256, x + ro * 256, scale,
        ppsum + (ro >> 6) * 256, ppsq + (ro >> 6) * 256);
  }

  // branch 2: bn2 partial-reduce (atomic-free) -> LIF -> fused FFN (in-place)
  bn_red_k<<<1, 256, 0, stream>>>(ppsum, ppsq, bn2_g, bn2_b, a2, b2);
  lif_k<<<PERT / 1024, 256, 0, stream>>>(x2, a2, b2, s2);
  ffn_fused_k<<<512, 512, 0, stream>>>(s2, ffn_w1b, ffn_b1, ffn_w2b, ffn_b2, x2, scale);
}